// Round 1
// baseline (816.577 us; speedup 1.0000x reference)
//
#include <hip/hip_runtime.h>
#include <stdint.h>

#define B_ 8
#define S_ 1024
#define D_ 1024
#define H_ 16
#define HD_ 64
#define KPAD 72    // 64 + 8 pad: byte stride 144 -> bank stride 4, conflict-free b128
#define PPAD 136   // 128 + 8 pad: byte stride 272

typedef short bf16x8 __attribute__((ext_vector_type(8)));
typedef float f32x4 __attribute__((ext_vector_type(4)));

__device__ __forceinline__ unsigned short f2bf(float f) {
    union { float f; unsigned int u; } v; v.f = f;
    unsigned int r = v.u + 0x7FFFu + ((v.u >> 16) & 1u);  // RNE
    return (unsigned short)(r >> 16);
}

// ---------------- cast x: f32 -> bf16 ----------------
__global__ __launch_bounds__(256) void cast_x_kernel(const float* __restrict__ x,
                                                     unsigned short* __restrict__ xb, int n4) {
    int i = blockIdx.x * 256 + threadIdx.x;
    if (i >= n4) return;
    float4 v = ((const float4*)x)[i];
    ushort4 o;
    o.x = f2bf(v.x); o.y = f2bf(v.y); o.z = f2bf(v.z); o.w = f2bf(v.w);
    ((ushort4*)xb)[i] = o;
}

// ---------------- transpose+cast W: Wt[z][n][k] = W_z[k][n] ----------------
__global__ __launch_bounds__(256) void transpose_w_kernel(const float* __restrict__ Wq,
                                                          const float* __restrict__ Wk,
                                                          const float* __restrict__ Wv,
                                                          unsigned short* __restrict__ Wt) {
    __shared__ float t[32][33];
    const int z = blockIdx.z;
    const float* W = (z == 0) ? Wq : (z == 1 ? Wk : Wv);
    int bx = blockIdx.x * 32, by = blockIdx.y * 32;
    int tx = threadIdx.x, ty = threadIdx.y;  // 32 x 8
    for (int i = 0; i < 4; i++)
        t[ty + 8 * i][tx] = W[(size_t)(by + ty + 8 * i) * D_ + bx + tx];
    __syncthreads();
    unsigned short* o = Wt + (size_t)z * D_ * D_;
    for (int i = 0; i < 4; i++)
        o[(size_t)(bx + ty + 8 * i) * D_ + by + tx] = f2bf(t[tx][ty + 8 * i]);
}

// ---------------- fused QKV projection: Y = (X @ W + b) * scale, bf16 out ----------------
// grid: x = 64 m-tiles, y = 24 (which*8 + n-tile). 128x128 tile, BK=64, 16x16x32 MFMA.
__global__ __launch_bounds__(256) void qkv_gemm_kernel(const unsigned short* __restrict__ Xb,
                                                       const unsigned short* __restrict__ Wt,
                                                       const float* __restrict__ bq,
                                                       const float* __restrict__ bk,
                                                       const float* __restrict__ bv,
                                                       unsigned short* __restrict__ Yb) {
    __shared__ unsigned short Xs[128 * KPAD];
    __shared__ unsigned short Ws[128 * KPAD];

    const int which = blockIdx.y >> 3;
    const int n0 = (blockIdx.y & 7) * 128;
    const int m0 = blockIdx.x * 128;
    const int tid = threadIdx.x;
    const int wave = tid >> 6, lane = tid & 63, quad = lane >> 4, l15 = lane & 15;

    const float* bias = (which == 0) ? bq : (which == 1 ? bk : bv);
    const float scale = (which == 0) ? 0.03125f : 1.0f;  // fold 1/sqrt(D)=1/32 into Q (exact, pow2)
    const unsigned short* Wm = Wt + (size_t)which * D_ * D_;

    f32x4 zero = {0.f, 0.f, 0.f, 0.f};
    f32x4 acc[2][8];
    for (int mt = 0; mt < 2; mt++)
        for (int nt = 0; nt < 8; nt++) acc[mt][nt] = zero;

    for (int kt = 0; kt < 16; kt++) {
        const int k0 = kt * 64;
        __syncthreads();
        for (int i = 0; i < 4; i++) {
            int c = tid + 256 * i;
            int row = c >> 3, cc = (c & 7) * 8;
            *(int4*)&Xs[row * KPAD + cc] = *(const int4*)&Xb[(size_t)(m0 + row) * D_ + k0 + cc];
            *(int4*)&Ws[row * KPAD + cc] = *(const int4*)&Wm[(size_t)(n0 + row) * D_ + k0 + cc];
        }
        __syncthreads();
        bf16x8 af[2][2];
        for (int mt = 0; mt < 2; mt++)
            for (int ks = 0; ks < 2; ks++)
                af[mt][ks] = *(const bf16x8*)&Xs[(wave * 32 + mt * 16 + l15) * KPAD + ks * 32 + quad * 8];
        for (int nt = 0; nt < 8; nt++) {
            bf16x8 b0 = *(const bf16x8*)&Ws[(nt * 16 + l15) * KPAD + quad * 8];
            bf16x8 b1 = *(const bf16x8*)&Ws[(nt * 16 + l15) * KPAD + 32 + quad * 8];
            for (int mt = 0; mt < 2; mt++) {
                acc[mt][nt] = __builtin_amdgcn_mfma_f32_16x16x32_bf16(af[mt][0], b0, acc[mt][nt], 0, 0, 0);
                acc[mt][nt] = __builtin_amdgcn_mfma_f32_16x16x32_bf16(af[mt][1], b1, acc[mt][nt], 0, 0, 0);
            }
        }
    }

    unsigned short* Y = Yb + (size_t)which * (size_t)(B_ * S_) * D_;
    for (int mt = 0; mt < 2; mt++) {
        int rbase = m0 + wave * 32 + mt * 16 + quad * 4;
        for (int nt = 0; nt < 8; nt++) {
            int col = n0 + nt * 16 + l15;
            float bcol = bias[col];
            for (int r = 0; r < 4; r++) {
                float v = (acc[mt][nt][r] + bcol) * scale;
                Y[(size_t)(rbase + r) * D_ + col] = f2bf(v);
            }
        }
    }
}

// ---------------- attention: two-pass softmax, writes attn_prob + out ----------------
// grid: x = 8 q-tiles, y = 128 (b*16 + h). block 256 (4 waves, 32 q-rows each).
__global__ __launch_bounds__(256) void attn_kernel(const unsigned short* __restrict__ Qb,
                                                   const unsigned short* __restrict__ Kb,
                                                   const unsigned short* __restrict__ Vb,
                                                   float* __restrict__ out,
                                                   float* __restrict__ attnp) {
    __shared__ unsigned short Ks[128 * KPAD];   // K-tile [s_local][hd]
    __shared__ unsigned short Vt[64 * PPAD];    // V-tile transposed [hd][s_local]
    __shared__ unsigned short Ps[128 * PPAD];   // P-tile bf16 [q_local][s_local]

    const int bh = blockIdx.y;
    const int b = bh >> 4, h = bh & 15;
    const int q0 = blockIdx.x * 128;
    const int tid = threadIdx.x;
    const int wave = tid >> 6, lane = tid & 63, quad = lane >> 4, l15 = lane & 15;

    // Q fragments held in registers for the whole block (A-operand layout)
    bf16x8 qf[2][2];
    for (int mt = 0; mt < 2; mt++)
        for (int ks = 0; ks < 2; ks++)
            qf[mt][ks] = *(const bf16x8*)&Qb[(size_t)(b * S_ + q0 + wave * 32 + mt * 16 + l15) * D_ +
                                            h * HD_ + ks * 32 + quad * 8];

    float mrun[2][4], lrun[2][4];
    for (int mt = 0; mt < 2; mt++)
        for (int r = 0; r < 4; r++) { mrun[mt][r] = -1e30f; lrun[mt][r] = 0.f; }

    f32x4 zero = {0.f, 0.f, 0.f, 0.f};

    // ---- pass 1: row max + sum(exp) (online) ----
    for (int kt = 0; kt < 8; kt++) {
        __syncthreads();
        for (int i = 0; i < 4; i++) {
            int c = tid + 256 * i;
            int row = c >> 3, cc = (c & 7) * 8;
            *(int4*)&Ks[row * KPAD + cc] = *(const int4*)&Kb[(size_t)(b * S_ + kt * 128 + row) * D_ + h * HD_ + cc];
        }
        __syncthreads();
        f32x4 acc[2][8];
        for (int mt = 0; mt < 2; mt++)
            for (int nt = 0; nt < 8; nt++) acc[mt][nt] = zero;
        for (int nt = 0; nt < 8; nt++) {
            bf16x8 b0 = *(const bf16x8*)&Ks[(nt * 16 + l15) * KPAD + quad * 8];
            bf16x8 b1 = *(const bf16x8*)&Ks[(nt * 16 + l15) * KPAD + 32 + quad * 8];
            for (int mt = 0; mt < 2; mt++) {
                acc[mt][nt] = __builtin_amdgcn_mfma_f32_16x16x32_bf16(qf[mt][0], b0, acc[mt][nt], 0, 0, 0);
                acc[mt][nt] = __builtin_amdgcn_mfma_f32_16x16x32_bf16(qf[mt][1], b1, acc[mt][nt], 0, 0, 0);
            }
        }
        for (int mt = 0; mt < 2; mt++) {
            for (int r = 0; r < 4; r++) {
                float tm = acc[mt][0][r];
                for (int nt = 1; nt < 8; nt++) tm = fmaxf(tm, acc[mt][nt][r]);
                for (int d = 1; d < 16; d <<= 1) tm = fmaxf(tm, __shfl_xor(tm, d));
                float mnew = fmaxf(mrun[mt][r], tm);
                float s = 0.f;
                for (int nt = 0; nt < 8; nt++) s += __expf(acc[mt][nt][r] - mnew);
                for (int d = 1; d < 16; d <<= 1) s += __shfl_xor(s, d);
                lrun[mt][r] = lrun[mt][r] * __expf(mrun[mt][r] - mnew) + s;
                mrun[mt][r] = mnew;
            }
        }
    }

    float invl[2][4];
    for (int mt = 0; mt < 2; mt++)
        for (int r = 0; r < 4; r++) invl[mt][r] = 1.0f / lrun[mt][r];

    f32x4 oacc[2][4];
    for (int mt = 0; mt < 2; mt++)
        for (int nv = 0; nv < 4; nv++) oacc[mt][nv] = zero;

    float* attn_base = attnp + (size_t)bh * S_ * S_;

    // ---- pass 2: final P (write f32 to global + bf16 to LDS) and O += P@V ----
    for (int kt = 0; kt < 8; kt++) {
        __syncthreads();
        for (int i = 0; i < 4; i++) {
            int c = tid + 256 * i;
            int row = c >> 3, cc = (c & 7) * 8;
            *(int4*)&Ks[row * KPAD + cc] = *(const int4*)&Kb[(size_t)(b * S_ + kt * 128 + row) * D_ + h * HD_ + cc];
            union { int4 v; unsigned short u[8]; } uu;
            uu.v = *(const int4*)&Vb[(size_t)(b * S_ + kt * 128 + row) * D_ + h * HD_ + cc];
            for (int j = 0; j < 8; j++) Vt[(cc + j) * PPAD + row] = uu.u[j];
        }
        __syncthreads();
        f32x4 acc[2][8];
        for (int mt = 0; mt < 2; mt++)
            for (int nt = 0; nt < 8; nt++) acc[mt][nt] = zero;
        for (int nt = 0; nt < 8; nt++) {
            bf16x8 b0 = *(const bf16x8*)&Ks[(nt * 16 + l15) * KPAD + quad * 8];
            bf16x8 b1 = *(const bf16x8*)&Ks[(nt * 16 + l15) * KPAD + 32 + quad * 8];
            for (int mt = 0; mt < 2; mt++) {
                acc[mt][nt] = __builtin_amdgcn_mfma_f32_16x16x32_bf16(qf[mt][0], b0, acc[mt][nt], 0, 0, 0);
                acc[mt][nt] = __builtin_amdgcn_mfma_f32_16x16x32_bf16(qf[mt][1], b1, acc[mt][nt], 0, 0, 0);
            }
        }
        for (int mt = 0; mt < 2; mt++) {
            int rl = wave * 32 + mt * 16 + quad * 4;
            for (int nt = 0; nt < 8; nt++) {
                int cl = nt * 16 + l15;
                for (int r = 0; r < 4; r++) {
                    float p = __expf(acc[mt][nt][r] - mrun[mt][r]) * invl[mt][r];
                    attn_base[(size_t)(q0 + rl + r) * S_ + kt * 128 + cl] = p;
                    Ps[(rl + r) * PPAD + cl] = f2bf(p);
                }
            }
        }
        __syncthreads();  // LDS fence: Ps/Vt visible before fragment reads
        for (int kc = 0; kc < 4; kc++) {
            bf16x8 af[2];
            for (int mt = 0; mt < 2; mt++)
                af[mt] = *(const bf16x8*)&Ps[(wave * 32 + mt * 16 + l15) * PPAD + kc * 32 + quad * 8];
            for (int nv = 0; nv < 4; nv++) {
                bf16x8 bf = *(const bf16x8*)&Vt[(nv * 16 + l15) * PPAD + kc * 32 + quad * 8];
                for (int mt = 0; mt < 2; mt++)
                    oacc[mt][nv] = __builtin_amdgcn_mfma_f32_16x16x32_bf16(af[mt], bf, oacc[mt][nv], 0, 0, 0);
            }
        }
    }

    for (int mt = 0; mt < 2; mt++) {
        int rbase = q0 + wave * 32 + mt * 16 + quad * 4;
        for (int nv = 0; nv < 4; nv++) {
            int col = h * HD_ + nv * 16 + l15;
            for (int r = 0; r < 4; r++)
                out[(size_t)(b * S_ + rbase + r) * D_ + col] = oacc[mt][nv][r];
        }
    }
}

extern "C" void kernel_launch(void* const* d_in, const int* in_sizes, int n_in,
                              void* d_out, int out_size, void* d_ws, size_t ws_size,
                              hipStream_t stream) {
    const float* x  = (const float*)d_in[0];
    const float* Wq = (const float*)d_in[1];
    const float* bq = (const float*)d_in[2];
    const float* Wk = (const float*)d_in[3];
    const float* bk = (const float*)d_in[4];
    const float* Wv = (const float*)d_in[5];
    const float* bv = (const float*)d_in[6];
    float* out = (float*)d_out;
    float* attnp = out + (size_t)B_ * S_ * D_;

    // workspace: Xb (16.8MB) | Wt x3 (6.3MB) | Q/K/V bf16 (50.3MB) = 73.4MB
    unsigned short* Xb = (unsigned short*)d_ws;
    unsigned short* Wt = Xb + (size_t)B_ * S_ * D_;
    unsigned short* Yb = Wt + (size_t)3 * D_ * D_;
    unsigned short* Qb = Yb;
    unsigned short* Kb = Yb + (size_t)B_ * S_ * D_;
    unsigned short* Vb = Kb + (size_t)B_ * S_ * D_;

    int n4 = B_ * S_ * D_ / 4;
    cast_x_kernel<<<(n4 + 255) / 256, 256, 0, stream>>>(x, Xb, n4);
    transpose_w_kernel<<<dim3(32, 32, 3), dim3(32, 8), 0, stream>>>(Wq, Wk, Wv, Wt);
    qkv_gemm_kernel<<<dim3(64, 24), 256, 0, stream>>>(Xb, Wt, bq, bk, bv, Yb);
    attn_kernel<<<dim3(8, 128), 256, 0, stream>>>(Qb, Kb, Vb, out, attnp);
}